// Round 4
// baseline (1507.500 us; speedup 1.0000x reference)
//
#include <hip/hip_runtime.h>
#include <math.h>

#define BATCH 8
#define CH    256
#define HWPIX 4096
#define CQK_  32

typedef __bf16 bf16x8 __attribute__((ext_vector_type(8)));
typedef __bf16 bf16x4 __attribute__((ext_vector_type(4)));
typedef __bf16 bf16x2 __attribute__((ext_vector_type(2)));
typedef float  f32x4  __attribute__((ext_vector_type(4)));

#define FS_STR 68   // LDS transpose-tile row stride in bf16 (136 B: 8B-aligned)

// load a bf16x8 fragment from LDS as two 8B halves (rows only 8B-aligned)
static __device__ inline bf16x8 ld_frag(const __bf16* p) {
  bf16x4 lo = *(const bf16x4*)p;
  bf16x4 hi = *(const bf16x4*)(p + 4);
  return __builtin_shufflevector(lo, hi, 0, 1, 2, 3, 4, 5, 6, 7);
}

// load 8 consecutive fp32 from a W row, convert to bf16x8 fragment
static __device__ inline bf16x8 w_frag(const float* p) {
  const float4 a = *(const float4*)p;
  const float4 b = *(const float4*)(p + 4);
  bf16x8 r;
  r[0] = (__bf16)a.x; r[1] = (__bf16)a.y; r[2] = (__bf16)a.z; r[3] = (__bf16)a.w;
  r[4] = (__bf16)b.x; r[5] = (__bf16)b.y; r[6] = (__bf16)b.z; r[7] = (__bf16)b.w;
  return r;
}

// ---- Fused projections. grid (64 n-tiles, 6 modes, 8 b), block 256 = 4 waves.
// mode 0: Q -> qT[b][n][32];  mode 1: K -> kT[b][n][32];
// mode 2..5: V c-tile (mode-2)*64 -> vv[b][c][hw].
__global__ __launch_bounds__(256, 6) void proj_all(
    const float* __restrict__ f1, const float* __restrict__ f2,
    const float* __restrict__ f3,
    const float* __restrict__ wq, const float* __restrict__ bq,
    const float* __restrict__ wk, const float* __restrict__ bk,
    const float* __restrict__ wv, const float* __restrict__ bv,
    __bf16* __restrict__ qT, __bf16* __restrict__ kT, __bf16* __restrict__ vv)
{
  __shared__ __align__(16) __bf16 f_s[64 * FS_STR];  // [n][cin] transposed tile
  const int t    = threadIdx.x;
  const int w    = __builtin_amdgcn_readfirstlane(t >> 6);
  const int lane = t & 63;
  const int q16  = lane & 15;
  const int quad = lane >> 4;
  const int b    = blockIdx.z;
  const int n0   = blockIdx.x * 64;
  const int mode = blockIdx.y;
  const bool isV = (mode >= 2);

  const float* f    = (mode == 0) ? f1 : (mode == 1) ? f2 : f3;
  const float* W    = (mode == 0) ? wq : (mode == 1) ? wk : wv;
  const float* bias = (mode == 0) ? bq : (mode == 1) ? bk : bv;
  const int cbase   = isV ? (mode - 2) * 64 : 0;

  const float* fb = f + (size_t)b * CH * HWPIX + n0;
  const int crow  = cbase + 16 * w + q16;  // V-path A-fragment row (c)

  f32x4 acc[4];
#pragma unroll
  for (int i = 0; i < 4; ++i) acc[i] = (f32x4){0.f, 0.f, 0.f, 0.f};

  for (int c0 = 0; c0 < CH; c0 += 64) {
    // ---- stage f[c0..+64)[n0..+64) -> f_s[n][cin] bf16 (transposed), float4 loads
    {
      const int n  = (t & 15) * 4;
      const int cp = (t >> 4) * 2;
#pragma unroll
      for (int rr = 0; rr < 2; ++rr) {
        const int c = rr * 32 + cp;
        const float4 a0 = *(const float4*)&fb[(size_t)(c0 + c) * HWPIX + n];
        const float4 a1 = *(const float4*)&fb[(size_t)(c0 + c + 1) * HWPIX + n];
#pragma unroll
        for (int i = 0; i < 4; ++i) {
          bf16x2 pk;
          pk[0] = (__bf16)((const float*)&a0)[i];
          pk[1] = (__bf16)((const float*)&a1)[i];
          *(bf16x2*)&f_s[(n + i) * FS_STR + c] = pk;
        }
      }
    }
    __syncthreads();

    if (!isV) {
      // A = f^T rows (n), B = W rows (o): acc[ot] (ot = o-halves)
      bf16x8 af[2];
#pragma unroll
      for (int kh = 0; kh < 2; ++kh)
        af[kh] = ld_frag(&f_s[(16 * w + q16) * FS_STR + 32 * kh + quad * 8]);
#pragma unroll
      for (int ot = 0; ot < 2; ++ot) {
#pragma unroll
        for (int kh = 0; kh < 2; ++kh) {
          const bf16x8 wf =
              w_frag(W + (size_t)(16 * ot + q16) * CH + c0 + 32 * kh + quad * 8);
          acc[ot] = __builtin_amdgcn_mfma_f32_16x16x32_bf16(af[kh], wf, acc[ot], 0, 0, 0);
        }
      }
    } else {
      // A = W rows (c), B = f^T rows (n): acc[nt]
      bf16x8 af[2];
#pragma unroll
      for (int kh = 0; kh < 2; ++kh)
        af[kh] = w_frag(W + (size_t)crow * CH + c0 + 32 * kh + quad * 8);
#pragma unroll
      for (int nt = 0; nt < 4; ++nt) {
#pragma unroll
        for (int kh = 0; kh < 2; ++kh) {
          const bf16x8 bfr = ld_frag(&f_s[(16 * nt + q16) * FS_STR + 32 * kh + quad * 8]);
          acc[nt] = __builtin_amdgcn_mfma_f32_16x16x32_bf16(af[kh], bfr, acc[nt], 0, 0, 0);
        }
      }
    }
    __syncthreads();
  }

  if (!isV) {
    const float bo0 = bias[q16];
    const float bo1 = bias[16 + q16];
    __bf16* outT = (mode == 0) ? qT : kT;
#pragma unroll
    for (int r = 0; r < 4; ++r) {
      const size_t row = (size_t)b * HWPIX + n0 + 16 * w + quad * 4 + r;
      outT[row * CQK_ + q16]      = (__bf16)(acc[0][r] + bo0);
      outT[row * CQK_ + 16 + q16] = (__bf16)(acc[1][r] + bo1);
    }
  } else {
    const float4 bi = *(const float4*)&bias[cbase + 16 * w + quad * 4];
#pragma unroll
    for (int nt = 0; nt < 4; ++nt) {
#pragma unroll
      for (int r = 0; r < 4; ++r) {
        const int c = cbase + 16 * w + quad * 4 + r;
        vv[((size_t)b * CH + c) * HWPIX + n0 + 16 * nt + q16] =
            (__bf16)(acc[nt][r] + ((const float*)&bi)[r]);
      }
    }
  }
}

// ---- Split-K flash attention. grid S*64*8; bx = (qt*S + s)*8 + b.
// Each block: keys [ms,me), writes unnormalized partial O (bf16) + partial L.
// Last-arriving block of each (qt,b) merges the S partials and writes out.
template <int S>
__global__ __launch_bounds__(256, 6) void attn_split(
    const __bf16* __restrict__ qT, const __bf16* __restrict__ kT,
    const __bf16* __restrict__ vv, __bf16* __restrict__ Op,
    float* __restrict__ Lg, unsigned int* __restrict__ cnt,
    float* __restrict__ out)
{
  __shared__ __align__(16) __bf16 p_s[64 * 72];  // [q][m], stride 72 bf16
  __shared__ float L_s[64];
  __shared__ unsigned int flag_s;

  const int t    = threadIdx.x;
  const int w    = __builtin_amdgcn_readfirstlane(t >> 6);
  const int lane = t & 63;
  const int q16  = lane & 15;
  const int quad = lane >> 4;

  const int b  = blockIdx.x & 7;
  const int g  = blockIdx.x >> 3;
  const int qt = g / S;
  const int s  = g % S;
  const int q0 = qt * 64;

  int ms, me;
  if (S == 3) { ms = s * 1344; me = (s == 2) ? HWPIX : ms + 1344; }
  else        { ms = 0; me = HWPIX; }

  const __bf16* kTb = kT + (size_t)b * HWPIX * CQK_;
  const __bf16* vbp = vv + ((size_t)b * CH + 64 * w) * HWPIX;

  const bf16x8 qfrag =
      *(const bf16x8*)(qT + ((size_t)b * HWPIX + q0 + 16 * w + q16) * CQK_ + quad * 8);

  f32x4 oacc[4][4];
#pragma unroll
  for (int i = 0; i < 4; ++i)
#pragma unroll
    for (int j = 0; j < 4; ++j)
      oacc[i][j] = (f32x4){0.f, 0.f, 0.f, 0.f};
  float Lp[4] = {0.f, 0.f, 0.f, 0.f};

  bf16x8 kf[4];
#pragma unroll
  for (int mt = 0; mt < 4; ++mt)
    kf[mt] = *(const bf16x8*)(kTb + (size_t)(ms + 16 * mt + q16) * CQK_ + quad * 8);

  for (int m0 = ms; m0 < me; m0 += 64) {
    f32x4 Sv[4];
#pragma unroll
    for (int mt = 0; mt < 4; ++mt)
      Sv[mt] = __builtin_amdgcn_mfma_f32_16x16x32_bf16(
          qfrag, kf[mt], (f32x4){0.f, 0.f, 0.f, 0.f}, 0, 0, 0);

    bf16x8 vf[4][2];
#pragma unroll
    for (int ct = 0; ct < 4; ++ct)
#pragma unroll
      for (int mh = 0; mh < 2; ++mh)
        vf[ct][mh] = *(const bf16x8*)(vbp + (size_t)(16 * ct + q16) * HWPIX
                                      + m0 + 32 * mh + quad * 8);

#pragma unroll
    for (int mt = 0; mt < 4; ++mt) {
#pragma unroll
      for (int r = 0; r < 4; ++r) {
        const float e = __expf(Sv[mt][r]);
        Lp[r] += e;
        p_s[(16 * w + quad * 4 + r) * 72 + 16 * mt + q16] = (__bf16)e;
      }
    }
    __syncthreads();

    int mn = m0 + 64;
    if (mn >= me) mn = ms;
#pragma unroll
    for (int mt = 0; mt < 4; ++mt)
      kf[mt] = *(const bf16x8*)(kTb + (size_t)(mn + 16 * mt + q16) * CQK_ + quad * 8);

    bf16x8 pf[4][2];
#pragma unroll
    for (int nt = 0; nt < 4; ++nt)
#pragma unroll
      for (int mh = 0; mh < 2; ++mh)
        pf[nt][mh] = *(const bf16x8*)(&p_s[(16 * nt + q16) * 72 + 32 * mh + quad * 8]);

#pragma unroll
    for (int ct = 0; ct < 4; ++ct)
#pragma unroll
      for (int nt = 0; nt < 4; ++nt)
#pragma unroll
        for (int mh = 0; mh < 2; ++mh)
          oacc[ct][nt] = __builtin_amdgcn_mfma_f32_16x16x32_bf16(
              vf[ct][mh], pf[nt][mh], oacc[ct][nt], 0, 0, 0);
    __syncthreads();
  }

  // ---- partial L: reduce across the 16 lanes of each row
#pragma unroll
  for (int r = 0; r < 4; ++r) {
    Lp[r] += __shfl_xor(Lp[r], 1);
    Lp[r] += __shfl_xor(Lp[r], 2);
    Lp[r] += __shfl_xor(Lp[r], 4);
    Lp[r] += __shfl_xor(Lp[r], 8);
  }
  if (q16 == 0) {
#pragma unroll
    for (int r = 0; r < 4; ++r) L_s[16 * w + quad * 4 + r] = Lp[r];
  }
  __syncthreads();
  if (t < 64) Lg[(size_t)(s * 8 + b) * HWPIX + q0 + t] = L_s[t];

  // ---- partial O store (unnormalized, bf16)
  __bf16* opb = Op + ((size_t)(s * 8 + b) * CH + 64 * w) * HWPIX + q0;
#pragma unroll
  for (int ct = 0; ct < 4; ++ct)
#pragma unroll
    for (int r = 0; r < 4; ++r)
#pragma unroll
      for (int nt = 0; nt < 4; ++nt)
        opb[(size_t)(16 * ct + quad * 4 + r) * HWPIX + 16 * nt + q16] =
            (__bf16)oacc[ct][nt][r];

  __threadfence();
  __syncthreads();
  if (t == 0) flag_s = atomicAdd(&cnt[qt * 8 + b], 1u);
  __syncthreads();
  if (flag_s != (unsigned)(S - 1)) return;

  // ---- merge: out = (sum_s Op_s) / (sum_s L_s). thread: 4 n x 16 c.
  const int n4 = q0 + (t & 15) * 4;
  const int cA = (t >> 4) * 16;
  float rL[4];
#pragma unroll
  for (int i = 0; i < 4; ++i) {
    float a = 0.f;
#pragma unroll
    for (int s2 = 0; s2 < S; ++s2)
      a += Lg[(size_t)(s2 * 8 + b) * HWPIX + n4 + i];
    rL[i] = 1.0f / a;
  }
  for (int cc = 0; cc < 16; ++cc) {
    const int c = cA + cc;
    float a[4] = {0.f, 0.f, 0.f, 0.f};
#pragma unroll
    for (int s2 = 0; s2 < S; ++s2) {
      const bf16x4 p =
          *(const bf16x4*)&Op[((size_t)(s2 * 8 + b) * CH + c) * HWPIX + n4];
#pragma unroll
      for (int i = 0; i < 4; ++i) a[i] += (float)p[i];
    }
    float4 o;
    o.x = a[0] * rL[0]; o.y = a[1] * rL[1];
    o.z = a[2] * rL[2]; o.w = a[3] * rL[3];
    *(float4*)&out[((size_t)b * CH + c) * HWPIX + n4] = o;
  }
}

extern "C" void kernel_launch(void* const* d_in, const int* in_sizes, int n_in,
                              void* d_out, int out_size, void* d_ws, size_t ws_size,
                              hipStream_t stream)
{
  const float* f1 = (const float*)d_in[0];
  const float* f2 = (const float*)d_in[1];
  const float* f3 = (const float*)d_in[2];
  const float* wq = (const float*)d_in[3];
  const float* bq = (const float*)d_in[4];
  const float* wk = (const float*)d_in[5];
  const float* bk = (const float*)d_in[6];
  const float* wv = (const float*)d_in[7];
  const float* bv = (const float*)d_in[8];
  float* outp = (float*)d_out;

  // ws layout: qT 2MB | kT 2MB | v 16MB | Op S*16.8MB | Lg S*128KB | cnt 2KB
  __bf16* qTw = (__bf16*)d_ws;
  __bf16* kTw = qTw + (size_t)BATCH * HWPIX * CQK_;
  __bf16* vw  = kTw + (size_t)BATCH * HWPIX * CQK_;
  char* base  = (char*)(vw + (size_t)BATCH * CH * HWPIX);

  const size_t opBytes1 = (size_t)BATCH * CH * HWPIX * sizeof(__bf16);
  const size_t lgBytes1 = (size_t)BATCH * HWPIX * sizeof(float);
  const size_t fixed    = (size_t)(base - (char*)d_ws);
  const size_t need3    = fixed + 3 * (opBytes1 + lgBytes1) + 2048;

  proj_all<<<dim3(64, 6, 8), 256, 0, stream>>>(f1, f2, f3, wq, bq, wk, bk, wv, bv,
                                               qTw, kTw, vw);

  if (ws_size >= need3) {
    __bf16* Op = (__bf16*)base;
    float* Lg  = (float*)(base + 3 * opBytes1);
    unsigned int* cnt = (unsigned int*)(base + 3 * (opBytes1 + lgBytes1));
    hipMemsetAsync(cnt, 0, 2048, stream);
    attn_split<3><<<dim3(3 * 64 * 8), 256, 0, stream>>>(qTw, kTw, vw, Op, Lg, cnt, outp);
  } else {
    __bf16* Op = (__bf16*)base;
    float* Lg  = (float*)(base + opBytes1);
    unsigned int* cnt = (unsigned int*)(base + opBytes1 + lgBytes1);
    hipMemsetAsync(cnt, 0, 2048, stream);
    attn_split<1><<<dim3(64 * 8), 256, 0, stream>>>(qTw, kTw, vw, Op, Lg, cnt, outp);
  }
}

// Round 5
// 314.342 us; speedup vs baseline: 4.7957x; 4.7957x over previous
//
#include <hip/hip_runtime.h>
#include <math.h>

#define BATCH 8
#define CH    256
#define HWPIX 4096
#define CQK_  32

typedef __bf16 bf16x8 __attribute__((ext_vector_type(8)));
typedef __bf16 bf16x4 __attribute__((ext_vector_type(4)));
typedef __bf16 bf16x2 __attribute__((ext_vector_type(2)));
typedef float  f32x4  __attribute__((ext_vector_type(4)));

#define FS_STR 68   // LDS transpose-tile row stride in bf16 (136 B: 8B-aligned)

// load a bf16x8 fragment from LDS as two 8B halves (rows only 8B-aligned)
static __device__ inline bf16x8 ld_frag(const __bf16* p) {
  bf16x4 lo = *(const bf16x4*)p;
  bf16x4 hi = *(const bf16x4*)(p + 4);
  return __builtin_shufflevector(lo, hi, 0, 1, 2, 3, 4, 5, 6, 7);
}

// load 8 consecutive fp32 from a W row, convert to bf16x8 fragment
static __device__ inline bf16x8 w_frag(const float* p) {
  const float4 a = *(const float4*)p;
  const float4 b = *(const float4*)(p + 4);
  bf16x8 r;
  r[0] = (__bf16)a.x; r[1] = (__bf16)a.y; r[2] = (__bf16)a.z; r[3] = (__bf16)a.w;
  r[4] = (__bf16)b.x; r[5] = (__bf16)b.y; r[6] = (__bf16)b.z; r[7] = (__bf16)b.w;
  return r;
}

// ---- Fused projections. grid (64 n-tiles, 3 modes, 8 b), block 256 = 4 waves.
// mode 0: Q -> qT[b][n][32] AND K -> kT[b][n][32] (both staged)
// mode 1,2: V c-half (mode-1)*128 -> vv[b][c][hw]
__global__ __launch_bounds__(256, 4) void proj_all(
    const float* __restrict__ f1, const float* __restrict__ f2,
    const float* __restrict__ f3,
    const float* __restrict__ wq, const float* __restrict__ bq,
    const float* __restrict__ wk, const float* __restrict__ bk,
    const float* __restrict__ wv, const float* __restrict__ bv,
    __bf16* __restrict__ qT, __bf16* __restrict__ kT, __bf16* __restrict__ vv)
{
  __shared__ __align__(16) __bf16 f_s[2][64 * FS_STR];  // [n][cin] transposed tiles
  const int t    = threadIdx.x;
  const int w    = __builtin_amdgcn_readfirstlane(t >> 6);
  const int lane = t & 63;
  const int q16  = lane & 15;
  const int quad = lane >> 4;
  const int b    = blockIdx.z;
  const int n0   = blockIdx.x * 64;
  const int mode = blockIdx.y;

  // staging helper: f[c0..+64)[n0..+64) -> dst[n][cin] bf16 (transposed)
  const int sn  = (t & 15) * 4;
  const int scp = (t >> 4) * 2;
#define STAGE(fb, c0, dst)                                                      \
  {                                                                             \
    _Pragma("unroll") for (int rr = 0; rr < 2; ++rr) {                          \
      const int c = rr * 32 + scp;                                              \
      const float4 a0 = *(const float4*)&(fb)[(size_t)((c0) + c) * HWPIX + sn]; \
      const float4 a1 = *(const float4*)&(fb)[(size_t)((c0) + c + 1) * HWPIX + sn]; \
      _Pragma("unroll") for (int i = 0; i < 4; ++i) {                           \
        bf16x2 pk;                                                              \
        pk[0] = (__bf16)((const float*)&a0)[i];                                 \
        pk[1] = (__bf16)((const float*)&a1)[i];                                 \
        *(bf16x2*)&(dst)[(sn + i) * FS_STR + c] = pk;                           \
      }                                                                         \
    }                                                                           \
  }

  if (mode == 0) {
    const float* f1b = f1 + (size_t)b * CH * HWPIX + n0;
    const float* f2b = f2 + (size_t)b * CH * HWPIX + n0;
    f32x4 accQ[2], accK[2];
#pragma unroll
    for (int i = 0; i < 2; ++i) {
      accQ[i] = (f32x4){0.f, 0.f, 0.f, 0.f};
      accK[i] = (f32x4){0.f, 0.f, 0.f, 0.f};
    }
    for (int c0 = 0; c0 < CH; c0 += 64) {
      STAGE(f1b, c0, f_s[0]);
      STAGE(f2b, c0, f_s[1]);
      __syncthreads();
      bf16x8 afQ[2], afK[2];
#pragma unroll
      for (int kh = 0; kh < 2; ++kh) {
        afQ[kh] = ld_frag(&f_s[0][(16 * w + q16) * FS_STR + 32 * kh + quad * 8]);
        afK[kh] = ld_frag(&f_s[1][(16 * w + q16) * FS_STR + 32 * kh + quad * 8]);
      }
#pragma unroll
      for (int ot = 0; ot < 2; ++ot) {
#pragma unroll
        for (int kh = 0; kh < 2; ++kh) {
          const bf16x8 wfq =
              w_frag(wq + (size_t)(16 * ot + q16) * CH + c0 + 32 * kh + quad * 8);
          accQ[ot] = __builtin_amdgcn_mfma_f32_16x16x32_bf16(afQ[kh], wfq, accQ[ot], 0, 0, 0);
          const bf16x8 wfk =
              w_frag(wk + (size_t)(16 * ot + q16) * CH + c0 + 32 * kh + quad * 8);
          accK[ot] = __builtin_amdgcn_mfma_f32_16x16x32_bf16(afK[kh], wfk, accK[ot], 0, 0, 0);
        }
      }
      __syncthreads();
    }
    const float bq0 = bq[q16], bq1 = bq[16 + q16];
    const float bk0 = bk[q16], bk1 = bk[16 + q16];
#pragma unroll
    for (int r = 0; r < 4; ++r) {
      const size_t row = (size_t)b * HWPIX + n0 + 16 * w + quad * 4 + r;
      qT[row * CQK_ + q16]      = (__bf16)(accQ[0][r] + bq0);
      qT[row * CQK_ + 16 + q16] = (__bf16)(accQ[1][r] + bq1);
      kT[row * CQK_ + q16]      = (__bf16)(accK[0][r] + bk0);
      kT[row * CQK_ + 16 + q16] = (__bf16)(accK[1][r] + bk1);
    }
  } else {
    const int cbase = (mode - 1) * 128;
    const float* f3b = f3 + (size_t)b * CH * HWPIX + n0;
    f32x4 acc[2][4];
#pragma unroll
    for (int ct = 0; ct < 2; ++ct)
#pragma unroll
      for (int nt = 0; nt < 4; ++nt) acc[ct][nt] = (f32x4){0.f, 0.f, 0.f, 0.f};

    for (int c0 = 0; c0 < CH; c0 += 64) {
      STAGE(f3b, c0, f_s[0]);
      __syncthreads();
      bf16x8 af[2][2];  // [ct][kh] : W rows (c)
#pragma unroll
      for (int ct = 0; ct < 2; ++ct)
#pragma unroll
        for (int kh = 0; kh < 2; ++kh)
          af[ct][kh] = w_frag(wv + (size_t)(cbase + 64 * ct + 16 * w + q16) * CH
                              + c0 + 32 * kh + quad * 8);
#pragma unroll
      for (int nt = 0; nt < 4; ++nt) {
#pragma unroll
        for (int kh = 0; kh < 2; ++kh) {
          const bf16x8 bfr = ld_frag(&f_s[0][(16 * nt + q16) * FS_STR + 32 * kh + quad * 8]);
#pragma unroll
          for (int ct = 0; ct < 2; ++ct)
            acc[ct][nt] = __builtin_amdgcn_mfma_f32_16x16x32_bf16(
                af[ct][kh], bfr, acc[ct][nt], 0, 0, 0);
        }
      }
      __syncthreads();
    }
#pragma unroll
    for (int ct = 0; ct < 2; ++ct) {
      const float4 bi = *(const float4*)&bv[cbase + 64 * ct + 16 * w + quad * 4];
#pragma unroll
      for (int nt = 0; nt < 4; ++nt) {
#pragma unroll
        for (int r = 0; r < 4; ++r) {
          const int c = cbase + 64 * ct + 16 * w + quad * 4 + r;
          vv[((size_t)b * CH + c) * HWPIX + n0 + 16 * nt + q16] =
              (__bf16)(acc[ct][nt][r] + ((const float*)&bi)[r]);
        }
      }
    }
  }
#undef STAGE
}

// ---- Pipelined flash attention, one barrier per key-tile, double-buffered P.
// grid 512: b = bx&7 (XCD-pinned), q-tile = bx>>3 (64 q). block 256 = 4 waves.
// Wave w: score rows q in [16w,16w+16); AV channels c in [64w, 64w+64).
__global__ __launch_bounds__(256, 2) void attn_kernel(
    const __bf16* __restrict__ qT, const __bf16* __restrict__ kT,
    const __bf16* __restrict__ vv, float* __restrict__ out)
{
  __shared__ __align__(16) __bf16 p_s[2][64 * 72];  // [q][m], stride 72 bf16
  __shared__ float L_s[64];

  const int t    = threadIdx.x;
  const int w    = __builtin_amdgcn_readfirstlane(t >> 6);
  const int lane = t & 63;
  const int q16  = lane & 15;
  const int quad = lane >> 4;

  const int b  = blockIdx.x & 7;
  const int q0 = (blockIdx.x >> 3) * 64;

  const __bf16* kTb = kT + (size_t)b * HWPIX * CQK_;
  const int koff = q16 * CQK_ + quad * 8;  // lane offset within a 64-key K tile

  // running V pointers, one per ct (advance 64 keys = 128 B per iter)
  const __bf16* vp[4];
#pragma unroll
  for (int ct = 0; ct < 4; ++ct)
    vp[ct] = vv + ((size_t)b * CH + 64 * w + 16 * ct + q16) * HWPIX + quad * 8;

  const bf16x8 qfrag =
      *(const bf16x8*)(qT + ((size_t)b * HWPIX + q0 + 16 * w + q16) * CQK_ + quad * 8);

  f32x4 oacc[4][4];
#pragma unroll
  for (int i = 0; i < 4; ++i)
#pragma unroll
    for (int j = 0; j < 4; ++j)
      oacc[i][j] = (f32x4){0.f, 0.f, 0.f, 0.f};
  float Lp[4] = {0.f, 0.f, 0.f, 0.f};

  // ---- prologue: scores tile 0 -> p_s[0]; kf <- tile 1
  bf16x8 kf[4];
#pragma unroll
  for (int mt = 0; mt < 4; ++mt)
    kf[mt] = *(const bf16x8*)(kTb + koff + mt * 512);
  {
    f32x4 Sv[4];
#pragma unroll
    for (int mt = 0; mt < 4; ++mt)
      Sv[mt] = __builtin_amdgcn_mfma_f32_16x16x32_bf16(
          qfrag, kf[mt], (f32x4){0.f, 0.f, 0.f, 0.f}, 0, 0, 0);
    const __bf16* kb1 = kTb + 64 * CQK_;
#pragma unroll
    for (int mt = 0; mt < 4; ++mt)
      kf[mt] = *(const bf16x8*)(kb1 + koff + mt * 512);
#pragma unroll
    for (int mt = 0; mt < 4; ++mt) {
#pragma unroll
      for (int r = 0; r < 4; ++r) {
        const float e = __expf(Sv[mt][r]);
        Lp[r] += e;
        p_s[0][(16 * w + quad * 4 + r) * 72 + 16 * mt + q16] = (__bf16)e;
      }
    }
  }
  __syncthreads();

  // ---- main loop: iter i does AV for tile i, scores+exp for tile i+1
  for (int i = 0; i < 64; ++i) {
    // V fragments for tile i (issued first; consumed after score/exp phase)
    bf16x8 vf[4][2];
#pragma unroll
    for (int ct = 0; ct < 4; ++ct)
#pragma unroll
      for (int mh = 0; mh < 2; ++mh)
        vf[ct][mh] = *(const bf16x8*)(vp[ct] + mh * 32);

    // P fragments for tile i from current buffer
    const __bf16* pb = p_s[i & 1];
    bf16x8 pf[4][2];
#pragma unroll
    for (int nt = 0; nt < 4; ++nt)
#pragma unroll
      for (int mh = 0; mh < 2; ++mh)
        pf[nt][mh] = *(const bf16x8*)(&pb[(16 * nt + q16) * 72 + 32 * mh + quad * 8]);

    if (i < 63) {
      // scores for tile i+1 (kf prefetched last iter)
      f32x4 Sv[4];
#pragma unroll
      for (int mt = 0; mt < 4; ++mt)
        Sv[mt] = __builtin_amdgcn_mfma_f32_16x16x32_bf16(
            qfrag, kf[mt], (f32x4){0.f, 0.f, 0.f, 0.f}, 0, 0, 0);
      // prefetch kf for tile i+2 (wave-uniform base -> SGPR + imm offsets)
      const __bf16* kb2 = kTb + (size_t)((i + 2) & 63) * (64 * CQK_);
#pragma unroll
      for (int mt = 0; mt < 4; ++mt)
        kf[mt] = *(const bf16x8*)(kb2 + koff + mt * 512);
      // exp + write P[i+1] into the other buffer
      __bf16* pw = p_s[(i + 1) & 1];
#pragma unroll
      for (int mt = 0; mt < 4; ++mt) {
#pragma unroll
        for (int r = 0; r < 4; ++r) {
          const float e = __expf(Sv[mt][r]);
          Lp[r] += e;
          pw[(16 * w + quad * 4 + r) * 72 + 16 * mt + q16] = (__bf16)e;
        }
      }
    }

    // AV for tile i
#pragma unroll
    for (int ct = 0; ct < 4; ++ct)
#pragma unroll
      for (int nt = 0; nt < 4; ++nt)
#pragma unroll
        for (int mh = 0; mh < 2; ++mh)
          oacc[ct][nt] = __builtin_amdgcn_mfma_f32_16x16x32_bf16(
              vf[ct][mh], pf[nt][mh], oacc[ct][nt], 0, 0, 0);

#pragma unroll
    for (int ct = 0; ct < 4; ++ct) vp[ct] += 64;
    __syncthreads();
  }

  // ---- finalize L: reduce partial sums across the 16 lanes of each row
#pragma unroll
  for (int r = 0; r < 4; ++r) {
    Lp[r] += __shfl_xor(Lp[r], 1);
    Lp[r] += __shfl_xor(Lp[r], 2);
    Lp[r] += __shfl_xor(Lp[r], 4);
    Lp[r] += __shfl_xor(Lp[r], 8);
  }
  if (q16 == 0) {
#pragma unroll
    for (int r = 0; r < 4; ++r) L_s[16 * w + quad * 4 + r] = Lp[r];
  }
  __syncthreads();

  float rinv[4];
#pragma unroll
  for (int nt = 0; nt < 4; ++nt) rinv[nt] = 1.0f / L_s[16 * nt + q16];

  float* ob = out + ((size_t)b * CH + 64 * w) * HWPIX + q0;
#pragma unroll
  for (int ct = 0; ct < 4; ++ct)
#pragma unroll
    for (int r = 0; r < 4; ++r)
#pragma unroll
      for (int nt = 0; nt < 4; ++nt)
        ob[(size_t)(16 * ct + quad * 4 + r) * HWPIX + 16 * nt + q16] =
            oacc[ct][nt][r] * rinv[nt];
}

extern "C" void kernel_launch(void* const* d_in, const int* in_sizes, int n_in,
                              void* d_out, int out_size, void* d_ws, size_t ws_size,
                              hipStream_t stream)
{
  const float* f1 = (const float*)d_in[0];
  const float* f2 = (const float*)d_in[1];
  const float* f3 = (const float*)d_in[2];
  const float* wq = (const float*)d_in[3];
  const float* bq = (const float*)d_in[4];
  const float* wk = (const float*)d_in[5];
  const float* bk = (const float*)d_in[6];
  const float* wv = (const float*)d_in[7];
  const float* bv = (const float*)d_in[8];
  float* outp = (float*)d_out;

  // workspace: qT [8][4096][32] | kT [8][4096][32] | v [8][256][4096]  (bf16, 20 MB)
  __bf16* qTw = (__bf16*)d_ws;
  __bf16* kTw = qTw + (size_t)BATCH * HWPIX * CQK_;
  __bf16* vw  = kTw + (size_t)BATCH * HWPIX * CQK_;

  proj_all<<<dim3(64, 3, 8), 256, 0, stream>>>(f1, f2, f3, wq, bq, wk, bk, wv, bv,
                                               qTw, kTw, vw);
  attn_kernel<<<dim3(512), 256, 0, stream>>>(qTw, kTw, vw, outp);
}